// Round 4
// baseline (586.631 us; speedup 1.0000x reference)
//
#include <hip/hip_runtime.h>

typedef float        f32x4  __attribute__((ext_vector_type(4)));
typedef __bf16       bf16x8 __attribute__((ext_vector_type(8)));

#define NN   8192
#define IND  256
#define OUTD 128
#define NB   144     // n: 0..127 = w*Wh cols, 128 = denominator, 129..143 = 0
#define KSPLIT 32
#define KRANGE 256   // 8 MFMA k-steps of 32
#define MSPLIT 32
#define MRANGE 256   // 8 m-iters of 32 rows (2 m-halves x 16)

__device__ __forceinline__ bf16x8 cvt2(f32x4 a, f32x4 b) {
  bf16x8 r;
  r[0]=(__bf16)a[0]; r[1]=(__bf16)a[1]; r[2]=(__bf16)a[2]; r[3]=(__bf16)a[3];
  r[4]=(__bf16)b[0]; r[5]=(__bf16)b[1]; r[6]=(__bf16)b[2]; r[7]=(__bf16)b[3];
  return r;
}

// K1: Wh = X @ W^T  [8192,128] fp32; e[j] = relu(Wh[j]) . a_w
__global__ __launch_bounds__(128) void k1_wh_e(const float* __restrict__ X,
                                               const float* __restrict__ W,
                                               const float* __restrict__ aw,
                                               float* __restrict__ Wh,
                                               float* __restrict__ ev) {
  const int lane = threadIdx.x & 63;
  const int wave = threadIdx.x >> 6;
  const int nlo  = lane & 15;
  const int quad = lane >> 4;
  const int rowBase = blockIdx.x * 32 + wave * 16;

  const float* xp = X + (size_t)(rowBase + nlo) * IND + quad * 8;
  f32x4 acc[8];
#pragma unroll
  for (int nt = 0; nt < 8; ++nt) acc[nt] = f32x4{0.f, 0.f, 0.f, 0.f};

#pragma unroll
  for (int kb = 0; kb < IND; kb += 32) {
    f32x4 a0 = *(const f32x4*)(xp + kb);
    f32x4 a1 = *(const f32x4*)(xp + kb + 4);
    bf16x8 af = cvt2(a0, a1);
#pragma unroll
    for (int nt = 0; nt < 8; ++nt) {
      const float* wp = W + (size_t)(nt * 16 + nlo) * IND + kb + quad * 8;
      f32x4 b0 = *(const f32x4*)wp;
      f32x4 b1 = *(const f32x4*)(wp + 4);
      acc[nt] = __builtin_amdgcn_mfma_f32_16x16x32_bf16(af, cvt2(b0, b1), acc[nt], 0, 0, 0);
    }
  }
  float p0 = 0.f, p1 = 0.f, p2 = 0.f, p3 = 0.f;
#pragma unroll
  for (int nt = 0; nt < 8; ++nt) {
    const int col = nt * 16 + nlo;
    const float awc = aw[col];
    const int r0 = rowBase + quad * 4;
    float v0 = acc[nt][0], v1 = acc[nt][1], v2 = acc[nt][2], v3 = acc[nt][3];
    Wh[(size_t)(r0 + 0) * OUTD + col] = v0;
    Wh[(size_t)(r0 + 1) * OUTD + col] = v1;
    Wh[(size_t)(r0 + 2) * OUTD + col] = v2;
    Wh[(size_t)(r0 + 3) * OUTD + col] = v3;
    p0 += fmaxf(v0, 0.f) * awc;
    p1 += fmaxf(v1, 0.f) * awc;
    p2 += fmaxf(v2, 0.f) * awc;
    p3 += fmaxf(v3, 0.f) * awc;
  }
#pragma unroll
  for (int off = 8; off; off >>= 1) {
    p0 += __shfl_xor(p0, off, 64);
    p1 += __shfl_xor(p1, off, 64);
    p2 += __shfl_xor(p2, off, 64);
    p3 += __shfl_xor(p3, off, 64);
  }
  if (nlo == 0) {
    const int r0 = rowBase + quad * 4;
    ev[r0 + 0] = p0; ev[r0 + 1] = p1; ev[r0 + 2] = p2; ev[r0 + 3] = p3;
  }
}

// K2: Bt [NB][NN] bf16: row n<128: w_j*Wh[j][n]; row 128: w_j; rows 129..143: 0
__global__ __launch_bounds__(256) void k2_bt(const float* __restrict__ Wh,
                                             const float* __restrict__ ev,
                                             __bf16* __restrict__ Bt) {
  const int j = blockIdx.x * 256 + threadIdx.x;
  const float w = expf(ev[j]);
  const int n0 = blockIdx.y * 18;
#pragma unroll
  for (int i = 0; i < 18; ++i) {
    const int n = n0 + i;
    float v = 0.f;
    if (n < OUTD) v = w * Wh[(size_t)j * OUTD + n];
    else if (n == OUTD) v = w;
    Bt[(size_t)n * NN + j] = (__bf16)v;
  }
}

// K3a: D[n,m] = sum_k Bt[n,k] * Adj[m,k] per k-slice. Bt frags persist in VGPRs
// (A-operand); adjacency streams as B-operand straight from global (no LDS, no
// barriers in the loop). 6 waves: wn = wave>>1 owns n-tiles {3wn..3wn+2},
// mh = wave&1 owns 16 of the iter's 32 rows. part layout [slice][m][NB].
__global__ __launch_bounds__(384, 3) void k3_partial(const float* __restrict__ Adj,
                                                     const __bf16* __restrict__ Bt,
                                                     float* __restrict__ part) {
  const int lane = threadIdx.x & 63;
  const int wave = threadIdx.x >> 6;
  const int wn   = wave >> 1;       // 0..2 : n-tile group
  const int mh   = wave & 1;        // 0..1 : m half
  const int nlo  = lane & 15;
  const int quad = lane >> 4;
  const int k0   = blockIdx.y * KRANGE;

  // persistent A-operand fragments: Bt[n = 48*wn + 16*t + nlo][k0 + 8*quad + 32*s]
  bf16x8 bfrag[3][8];
#pragma unroll
  for (int t = 0; t < 3; ++t) {
    const __bf16* bp = Bt + (size_t)(48 * wn + 16 * t + nlo) * NN + k0 + quad * 8;
#pragma unroll
    for (int s = 0; s < 8; ++s)
      bfrag[t][s] = *(const bf16x8*)(bp + s * 32);
  }

  const int mBase = blockIdx.x * MRANGE + mh * 16;
  const float* ap0 = Adj + (size_t)(mBase + nlo) * NN + k0 + quad * 8;
  float* pbase = part + ((size_t)blockIdx.y * NN + mBase + nlo) * NB + 48 * wn + quad * 4;

  for (int it = 0; it < MRANGE / 32; ++it) {
    const float* ap = ap0 + (size_t)it * 32 * NN;
    f32x4 av[16];
#pragma unroll
    for (int s = 0; s < 8; ++s) {
      av[2 * s]     = *(const f32x4*)(ap + s * 32);
      av[2 * s + 1] = *(const f32x4*)(ap + s * 32 + 4);
    }
    f32x4 acc[3];
#pragma unroll
    for (int t = 0; t < 3; ++t) acc[t] = f32x4{0.f, 0.f, 0.f, 0.f};
#pragma unroll
    for (int s = 0; s < 8; ++s) {
      bf16x8 af = cvt2(av[2 * s], av[2 * s + 1]);
#pragma unroll
      for (int t = 0; t < 3; ++t)
        acc[t] = __builtin_amdgcn_mfma_f32_16x16x32_bf16(bfrag[t][s], af, acc[t], 0, 0, 0);
    }
    // D: col(lane&15)=m offset, row(quad*4+rg)=n offset. Store [m][n]-major.
    float* pb = pbase + (size_t)it * 32 * NB;
#pragma unroll
    for (int t = 0; t < 3; ++t)
#pragma unroll
      for (int rg = 0; rg < 4; ++rg)
        __builtin_nontemporal_store(acc[t][rg], pb + 16 * t + rg);
  }
}

// K3b: out[m][n] = relu( sum_s part[s][m][n] / sum_s part[s][m][128] )
__global__ __launch_bounds__(256) void k3_reduce(const float* __restrict__ part,
                                                 float* __restrict__ out) {
  const int n = threadIdx.x & 127;
  const int m = blockIdx.x * 2 + (threadIdx.x >> 7);
  float num = 0.f, den = 0.f;
#pragma unroll
  for (int s = 0; s < KSPLIT; ++s) {
    const float* pr = part + ((size_t)s * NN + m) * NB;
    num += pr[n];
    den += pr[128];
  }
  out[(size_t)m * OUTD + n] = fmaxf(num / den, 0.f);
}

extern "C" void kernel_launch(void* const* d_in, const int* in_sizes, int n_in,
                              void* d_out, int out_size, void* d_ws, size_t ws_size,
                              hipStream_t stream) {
  const float* X  = (const float*)d_in[0];
  const float* A  = (const float*)d_in[1];
  const float* W  = (const float*)d_in[2];
  const float* aw = (const float*)d_in[3];
  float* out = (float*)d_out;

  char* ws = (char*)d_ws;
  float*  Wh   = (float*)ws;                    // 8192*128*4     = 4 MiB
  float*  ev   = (float*)(ws + 4194304);        // 8192*4         = 32 KiB
  __bf16* Bt   = (__bf16*)(ws + 4227072);       // 144*8192*2     = 2.25 MiB
  float*  part = (float*)(ws + 8388608);        // 32*8192*144*4  = 151 MiB

  k1_wh_e<<<256, 128, 0, stream>>>(X, W, aw, Wh, ev);
  k2_bt<<<dim3(32, 8), 256, 0, stream>>>(Wh, ev, Bt);
  k3_partial<<<dim3(MSPLIT, KSPLIT), 384, 0, stream>>>(A, Bt, part);
  k3_reduce<<<4096, 256, 0, stream>>>(part, out);
}

// Round 5
// 530.435 us; speedup vs baseline: 1.1059x; 1.1059x over previous
//
#include <hip/hip_runtime.h>

typedef float        f32x4  __attribute__((ext_vector_type(4)));
typedef __bf16       bf16x8 __attribute__((ext_vector_type(8)));

#define NN   8192
#define IND  256
#define OUTD 128
#define NB   144     // n: 0..127 = B cols, 128 = denominator, 129..143 = 0
#define NT   9       // n-tiles of 16
#define KSPLIT 8
#define KTILES 32    // ktiles (of 32 k) per k-slice: 8*32*32 = 8192

__device__ __forceinline__ bf16x8 cvt2(f32x4 a, f32x4 b) {
  bf16x8 r;
  r[0]=(__bf16)a[0]; r[1]=(__bf16)a[1]; r[2]=(__bf16)a[2]; r[3]=(__bf16)a[3];
  r[4]=(__bf16)b[0]; r[5]=(__bf16)b[1]; r[6]=(__bf16)b[2]; r[7]=(__bf16)b[3];
  return r;
}

// K1: Wh = X @ W^T  [8192,128] fp32; e[j] = relu(Wh[j]) . a_w
__global__ __launch_bounds__(128) void k1_wh_e(const float* __restrict__ X,
                                               const float* __restrict__ W,
                                               const float* __restrict__ aw,
                                               float* __restrict__ Wh,
                                               float* __restrict__ ev) {
  const int lane = threadIdx.x & 63;
  const int wave = threadIdx.x >> 6;
  const int nlo  = lane & 15;
  const int quad = lane >> 4;
  const int rowBase = blockIdx.x * 32 + wave * 16;

  const float* xp = X + (size_t)(rowBase + nlo) * IND + quad * 8;
  f32x4 acc[8];
#pragma unroll
  for (int nt = 0; nt < 8; ++nt) acc[nt] = f32x4{0.f, 0.f, 0.f, 0.f};

#pragma unroll
  for (int kb = 0; kb < IND; kb += 32) {
    f32x4 a0 = *(const f32x4*)(xp + kb);
    f32x4 a1 = *(const f32x4*)(xp + kb + 4);
    bf16x8 af = cvt2(a0, a1);
#pragma unroll
    for (int nt = 0; nt < 8; ++nt) {
      const float* wp = W + (size_t)(nt * 16 + nlo) * IND + kb + quad * 8;
      f32x4 b0 = *(const f32x4*)wp;
      f32x4 b1 = *(const f32x4*)(wp + 4);
      acc[nt] = __builtin_amdgcn_mfma_f32_16x16x32_bf16(af, cvt2(b0, b1), acc[nt], 0, 0, 0);
    }
  }
  float p0 = 0.f, p1 = 0.f, p2 = 0.f, p3 = 0.f;
#pragma unroll
  for (int nt = 0; nt < 8; ++nt) {
    const int col = nt * 16 + nlo;
    const float awc = aw[col];
    const int r0 = rowBase + quad * 4;
    float v0 = acc[nt][0], v1 = acc[nt][1], v2 = acc[nt][2], v3 = acc[nt][3];
    Wh[(size_t)(r0 + 0) * OUTD + col] = v0;
    Wh[(size_t)(r0 + 1) * OUTD + col] = v1;
    Wh[(size_t)(r0 + 2) * OUTD + col] = v2;
    Wh[(size_t)(r0 + 3) * OUTD + col] = v3;
    p0 += fmaxf(v0, 0.f) * awc;
    p1 += fmaxf(v1, 0.f) * awc;
    p2 += fmaxf(v2, 0.f) * awc;
    p3 += fmaxf(v3, 0.f) * awc;
  }
#pragma unroll
  for (int off = 8; off; off >>= 1) {
    p0 += __shfl_xor(p0, off, 64);
    p1 += __shfl_xor(p1, off, 64);
    p2 += __shfl_xor(p2, off, 64);
    p3 += __shfl_xor(p3, off, 64);
  }
  if (nlo == 0) {
    const int r0 = rowBase + quad * 4;
    ev[r0 + 0] = p0; ev[r0 + 1] = p1; ev[r0 + 2] = p2; ev[r0 + 3] = p3;
  }
}

// K2: pack B into MFMA B-fragment-linear layout.
// Block (T,u) of Bp is 64 lanes x 8 bf16 contiguous (1 KB):
//   Bp[((T*NT+u)*64 + lane)*8 + j] = B[k = 32T + (lane>>4)*8 + j][n = 16u + (lane&15)]
// where B[k][n] = exp(e_k)*Wh[k][n] (n<128), exp(e_k) (n==128), 0 (n>128).
__global__ __launch_bounds__(64) void k2_pack(const float* __restrict__ Wh,
                                              const float* __restrict__ ev,
                                              __bf16* __restrict__ Bp) {
  const int T = blockIdx.x, u = blockIdx.y;
  const int lane = threadIdx.x;
  const int nlo  = lane & 15;
  const int kbase = T * 32 + (lane >> 4) * 8;
  bf16x8 o;
  if (u < 8) {
#pragma unroll
    for (int j = 0; j < 8; ++j) {
      const float wk = expf(ev[kbase + j]);
      o[j] = (__bf16)(wk * Wh[(size_t)(kbase + j) * OUTD + u * 16 + nlo]);
    }
  } else {
#pragma unroll
    for (int j = 0; j < 8; ++j)
      o[j] = (nlo == 0) ? (__bf16)expf(ev[kbase + j]) : (__bf16)0.f;
  }
  *(bf16x8*)(Bp + ((size_t)(T * NT + u) * 64 + lane) * 8) = o;
}

// K3a: part[s][m][NB] = Adj(->bf16) @ B over the slice's 1024-k range.
// Grid (128, KSPLIT) x 256 thr; wave = 16 m-rows. No LDS, no barriers:
// B streams fragment-linear from L1/L2, A streams coalesced from HBM/L3.
// Explicit depth-2 register rotation forces rolling vmcnt (software pipeline).
__global__ __launch_bounds__(256, 3) void k3_partial(const float* __restrict__ Adj,
                                                     const __bf16* __restrict__ Bp,
                                                     float* __restrict__ part) {
  const int lane = threadIdx.x & 63;
  const int wave = threadIdx.x >> 6;
  const int nlo  = lane & 15;
  const int quad = lane >> 4;
  const int mBase = blockIdx.x * 64 + wave * 16;
  const int Tbase = blockIdx.y * KTILES;

  const float*  ap = Adj + (size_t)(mBase + nlo) * NN + Tbase * 32 + quad * 8;
  const __bf16* bq = Bp + (size_t)Tbase * NT * 512 + (size_t)lane * 8;

  f32x4 acc[NT];
#pragma unroll
  for (int t = 0; t < NT; ++t) acc[t] = f32x4{0.f, 0.f, 0.f, 0.f};

  bf16x8 bb[2][NT];
  f32x4  aa[2][2];
  // prologue: kstep 0
#pragma unroll
  for (int t = 0; t < NT; ++t) bb[0][t] = *(const bf16x8*)(bq + t * 512);
  aa[0][0] = *(const f32x4*)(ap);
  aa[0][1] = *(const f32x4*)(ap + 4);

#pragma unroll
  for (int ks = 0; ks < KTILES; ++ks) {
    const int cur = ks & 1, nxt = cur ^ 1;
    if (ks < KTILES - 1) {
      const __bf16* bn = bq + (size_t)(ks + 1) * NT * 512;
#pragma unroll
      for (int t = 0; t < NT; ++t) bb[nxt][t] = *(const bf16x8*)(bn + t * 512);
      const float* an = ap + (ks + 1) * 32;
      aa[nxt][0] = *(const f32x4*)(an);
      aa[nxt][1] = *(const f32x4*)(an + 4);
    }
    bf16x8 af = cvt2(aa[cur][0], aa[cur][1]);
#pragma unroll
    for (int t = 0; t < NT; ++t)
      acc[t] = __builtin_amdgcn_mfma_f32_16x16x32_bf16(af, bb[cur][t], acc[t], 0, 0, 0);
  }

  // D: row = quad*4+rg -> m offset, col = lane&15 -> n offset (within tile t)
#pragma unroll
  for (int t = 0; t < NT; ++t)
#pragma unroll
    for (int rg = 0; rg < 4; ++rg)
      part[((size_t)blockIdx.y * NN + mBase + quad * 4 + rg) * NB + t * 16 + nlo] = acc[t][rg];
}

// K3b: out[m][n] = relu( sum_s part[s][m][n] / sum_s part[s][m][128] )
__global__ __launch_bounds__(256) void k3_reduce(const float* __restrict__ part,
                                                 float* __restrict__ out) {
  const int n = threadIdx.x & 127;
  const int m = blockIdx.x * 2 + (threadIdx.x >> 7);
  float num = 0.f, den = 0.f;
#pragma unroll
  for (int s = 0; s < KSPLIT; ++s) {
    const float* pr = part + ((size_t)s * NN + m) * NB;
    num += pr[n];
    den += pr[128];
  }
  out[(size_t)m * OUTD + n] = fmaxf(num / den, 0.f);
}

extern "C" void kernel_launch(void* const* d_in, const int* in_sizes, int n_in,
                              void* d_out, int out_size, void* d_ws, size_t ws_size,
                              hipStream_t stream) {
  const float* X  = (const float*)d_in[0];
  const float* A  = (const float*)d_in[1];
  const float* W  = (const float*)d_in[2];
  const float* aw = (const float*)d_in[3];
  float* out = (float*)d_out;

  char* ws = (char*)d_ws;
  float*  Wh   = (float*)ws;                    // 8192*128*4    = 4 MiB
  float*  ev   = (float*)(ws + 4194304);        // 8192*4        = 32 KiB
  __bf16* Bp   = (__bf16*)(ws + 4227072);       // 256*9*64*8*2  = 2.25 MiB
  float*  part = (float*)(ws + 8388608);        // 8*8192*144*4  = 37.75 MiB

  k1_wh_e<<<256, 128, 0, stream>>>(X, W, aw, Wh, ev);
  k2_pack<<<dim3(256, NT), 64, 0, stream>>>(Wh, ev, Bp);
  k3_partial<<<dim3(128, KSPLIT), 256, 0, stream>>>(A, Bp, part);
  k3_reduce<<<4096, 256, 0, stream>>>(part, out);
}

// Round 7
// 462.864 us; speedup vs baseline: 1.2674x; 1.1460x over previous
//
#include <hip/hip_runtime.h>

typedef float        f32x4  __attribute__((ext_vector_type(4)));
typedef __bf16       bf16x8 __attribute__((ext_vector_type(8)));

#define NN   8192
#define IND  256
#define OUTD 128
#define NB   144     // n: 0..127 = B cols, 128 = denominator, 129..143 = 0
#define NT   9       // n-tiles of 16
#define KSPLIT 8
#define KTILES 32    // 32-k tiles per slice: 8 * 32 * 32 = 8192

// async global->LDS, 16B per lane; lds base must be wave-uniform
#define GLD_LDS16(gp, lp)                                                     \
  __builtin_amdgcn_global_load_lds(                                           \
      (__attribute__((address_space(1))) const void*)(gp),                    \
      (__attribute__((address_space(3))) void*)(lp), 16, 0, 0)

#define MEMFENCE asm volatile("" ::: "memory")
#define WAITV(n) asm volatile("s_waitcnt vmcnt(" #n ")" ::: "memory")

__device__ __forceinline__ bf16x8 cvt2(f32x4 a, f32x4 b) {
  bf16x8 r;
  r[0]=(__bf16)a[0]; r[1]=(__bf16)a[1]; r[2]=(__bf16)a[2]; r[3]=(__bf16)a[3];
  r[4]=(__bf16)b[0]; r[5]=(__bf16)b[1]; r[6]=(__bf16)b[2]; r[7]=(__bf16)b[3];
  return r;
}

// K1: Wh = X @ W^T  [8192,128] fp32; e[j] = relu(Wh[j]) . a_w
__global__ __launch_bounds__(128) void k1_wh_e(const float* __restrict__ X,
                                               const float* __restrict__ W,
                                               const float* __restrict__ aw,
                                               float* __restrict__ Wh,
                                               float* __restrict__ ev) {
  const int lane = threadIdx.x & 63;
  const int wave = threadIdx.x >> 6;
  const int nlo  = lane & 15;
  const int quad = lane >> 4;
  const int rowBase = blockIdx.x * 32 + wave * 16;

  const float* xp = X + (size_t)(rowBase + nlo) * IND + quad * 8;
  f32x4 acc[8];
#pragma unroll
  for (int nt = 0; nt < 8; ++nt) acc[nt] = f32x4{0.f, 0.f, 0.f, 0.f};

#pragma unroll
  for (int kb = 0; kb < IND; kb += 32) {
    f32x4 a0 = *(const f32x4*)(xp + kb);
    f32x4 a1 = *(const f32x4*)(xp + kb + 4);
    bf16x8 af = cvt2(a0, a1);
#pragma unroll
    for (int nt = 0; nt < 8; ++nt) {
      const float* wp = W + (size_t)(nt * 16 + nlo) * IND + kb + quad * 8;
      f32x4 b0 = *(const f32x4*)wp;
      f32x4 b1 = *(const f32x4*)(wp + 4);
      acc[nt] = __builtin_amdgcn_mfma_f32_16x16x32_bf16(af, cvt2(b0, b1), acc[nt], 0, 0, 0);
    }
  }
  float p0 = 0.f, p1 = 0.f, p2 = 0.f, p3 = 0.f;
#pragma unroll
  for (int nt = 0; nt < 8; ++nt) {
    const int col = nt * 16 + nlo;
    const float awc = aw[col];
    const int r0 = rowBase + quad * 4;
    float v0 = acc[nt][0], v1 = acc[nt][1], v2 = acc[nt][2], v3 = acc[nt][3];
    Wh[(size_t)(r0 + 0) * OUTD + col] = v0;
    Wh[(size_t)(r0 + 1) * OUTD + col] = v1;
    Wh[(size_t)(r0 + 2) * OUTD + col] = v2;
    Wh[(size_t)(r0 + 3) * OUTD + col] = v3;
    p0 += fmaxf(v0, 0.f) * awc;
    p1 += fmaxf(v1, 0.f) * awc;
    p2 += fmaxf(v2, 0.f) * awc;
    p3 += fmaxf(v3, 0.f) * awc;
  }
#pragma unroll
  for (int off = 8; off; off >>= 1) {
    p0 += __shfl_xor(p0, off, 64);
    p1 += __shfl_xor(p1, off, 64);
    p2 += __shfl_xor(p2, off, 64);
    p3 += __shfl_xor(p3, off, 64);
  }
  if (nlo == 0) {
    const int r0 = rowBase + quad * 4;
    ev[r0 + 0] = p0; ev[r0 + 1] = p1; ev[r0 + 2] = p2; ev[r0 + 3] = p3;
  }
}

// K2: pack B into MFMA B-fragment-linear layout.
//   Bp[((T*NT+u)*64 + lane)*8 + j] = B[k = 32T + (lane>>4)*8 + j][n = 16u + (lane&15)]
// B[k][n] = exp(e_k)*Wh[k][n] (n<128), exp(e_k) (n==128), 0 (n>128).
__global__ __launch_bounds__(64) void k2_pack(const float* __restrict__ Wh,
                                              const float* __restrict__ ev,
                                              __bf16* __restrict__ Bp) {
  const int T = blockIdx.x, u = blockIdx.y;
  const int lane = threadIdx.x;
  const int nlo  = lane & 15;
  const int kbase = T * 32 + (lane >> 4) * 8;
  bf16x8 o;
  if (u < 8) {
#pragma unroll
    for (int j = 0; j < 8; ++j) {
      const float wk = expf(ev[kbase + j]);
      o[j] = (__bf16)(wk * Wh[(size_t)(kbase + j) * OUTD + u * 16 + nlo]);
    }
  } else {
#pragma unroll
    for (int j = 0; j < 8; ++j)
      o[j] = (nlo == 0) ? (__bf16)expf(ev[kbase + j]) : (__bf16)0.f;
  }
  *(bf16x8*)(Bp + ((size_t)(T * NT + u) * 64 + lane) * 8) = o;
}

// K3a: part[s][m][NB] = Adj(->bf16) @ B over the slice's 1024-k range.
// Grid (64, KSPLIT) x 256. Wave owns 32 private m-rows -> per-wave LDS
// TRIPLE-buffer filled by async global_load_lds at prefetch distance 2;
// NO barriers. Explicit conservatively-counted vmcnt waits close the
// DMA->ds_read race (compiler does not track that dependency).
__global__ __launch_bounds__(256, 3) void k3_partial(const float* __restrict__ Adj,
                                                     const __bf16* __restrict__ Bp,
                                                     float* __restrict__ part) {
  __shared__ float AL[4][3][1024];  // [wave][buf][m*32+k] : 48 KB
  const int lane = threadIdx.x & 63;
  const int wave = threadIdx.x >> 6;
  const int nlo  = lane & 15;
  const int quad = lane >> 4;
  const int mWave = blockIdx.x * 128 + wave * 32;
  const int kbase = blockIdx.y * (KTILES * 32);

  // DMA source: lane fetches Adj[mWave + i*8 + lane/8][k + (lane&7)*4 ..+4)
  const float* gsrc = Adj + (size_t)(mWave + (lane >> 3)) * NN + kbase + (lane & 7) * 4;

  f32x4 acc[2][NT];
#pragma unroll
  for (int g = 0; g < 2; ++g)
#pragma unroll
    for (int t = 0; t < NT; ++t) acc[g][t] = f32x4{0.f, 0.f, 0.f, 0.f};

  // prologue: stage chunks 0 and 1
#pragma unroll
  for (int i = 0; i < 4; ++i)
    GLD_LDS16(gsrc + (size_t)(i * 8) * NN, &AL[wave][0][i * 256]);
#pragma unroll
  for (int i = 0; i < 4; ++i)
    GLD_LDS16(gsrc + (size_t)(i * 8) * NN + 32, &AL[wave][1][i * 256]);

  const __bf16* bq = Bp + (size_t)(blockIdx.y * KTILES) * NT * 512 + (size_t)lane * 8;

#pragma unroll
  for (int c = 0; c < KTILES; ++c) {
    MEMFENCE;  // iteration boundary: no cross-iter reordering of memory ops
    // B fragments for chunk c (9 x dwordx4; compiler handles their reg waits)
    bf16x8 bf[NT];
#pragma unroll
    for (int t = 0; t < NT; ++t)
      bf[t] = *(const bf16x8*)(bq + ((size_t)c * NT + t) * 512);
    // stage chunk c+2
    if (c + 2 < KTILES) {
#pragma unroll
      for (int i = 0; i < 4; ++i)
        GLD_LDS16(gsrc + (size_t)(i * 8) * NN + (c + 2) * 32,
                  &AL[wave][(c + 2) % 3][i * 256]);
    }
    // Guarantee DMA(c) landed before ds_read. FIFO vmcnt: ops provably issued
    // after DMA(c): c==0 -> 17, main -> 26, c==KT-2 -> 22, c==KT-1 -> 18.
    // Steady-state these are no-ops (keep DMA c+1, c+2 and B(c) in flight).
    if (c == 0)                WAITV(17);
    else if (c < KTILES - 2)   WAITV(26);
    else if (c == KTILES - 2)  WAITV(22);
    else                       WAITV(18);

    const float* abuf = &AL[wave][c % 3][0];
#pragma unroll
    for (int g = 0; g < 2; ++g) {
      f32x4 a0 = *(const f32x4*)(abuf + (g * 16 + nlo) * 32 + quad * 8);
      f32x4 a1 = *(const f32x4*)(abuf + (g * 16 + nlo) * 32 + quad * 8 + 4);
      bf16x8 af = cvt2(a0, a1);
#pragma unroll
      for (int t = 0; t < NT; ++t)
        acc[g][t] = __builtin_amdgcn_mfma_f32_16x16x32_bf16(af, bf[t], acc[g][t], 0, 0, 0);
    }
  }

  // D: row = quad*4+rg -> m offset, col = lane&15 -> n offset (tile t)
#pragma unroll
  for (int g = 0; g < 2; ++g)
#pragma unroll
    for (int t = 0; t < NT; ++t)
#pragma unroll
      for (int rg = 0; rg < 4; ++rg)
        part[((size_t)blockIdx.y * NN + mWave + g * 16 + quad * 4 + rg) * NB + t * 16 + nlo] =
            acc[g][t][rg];
}

// K3b: out[m][n] = relu( sum_s part[s][m][n] / sum_s part[s][m][128] )
__global__ __launch_bounds__(256) void k3_reduce(const float* __restrict__ part,
                                                 float* __restrict__ out) {
  const int n = threadIdx.x & 127;
  const int m = blockIdx.x * 2 + (threadIdx.x >> 7);
  float num = 0.f, den = 0.f;
#pragma unroll
  for (int s = 0; s < KSPLIT; ++s) {
    const float* pr = part + ((size_t)s * NN + m) * NB;
    num += pr[n];
    den += pr[128];
  }
  out[(size_t)m * OUTD + n] = fmaxf(num / den, 0.f);
}

extern "C" void kernel_launch(void* const* d_in, const int* in_sizes, int n_in,
                              void* d_out, int out_size, void* d_ws, size_t ws_size,
                              hipStream_t stream) {
  const float* X  = (const float*)d_in[0];
  const float* A  = (const float*)d_in[1];
  const float* W  = (const float*)d_in[2];
  const float* aw = (const float*)d_in[3];
  float* out = (float*)d_out;

  char* ws = (char*)d_ws;
  float*  Wh   = (float*)ws;                    // 8192*128*4    = 4 MiB
  float*  ev   = (float*)(ws + 4194304);        // 8192*4        = 32 KiB
  __bf16* Bp   = (__bf16*)(ws + 4227072);       // 256*9*512*2   = 2.25 MiB
  float*  part = (float*)(ws + 8388608);        // 8*8192*144*4  = 37.75 MiB

  k1_wh_e<<<256, 128, 0, stream>>>(X, W, aw, Wh, ev);
  k2_pack<<<dim3(256, NT), 64, 0, stream>>>(Wh, ev, Bp);
  k3_partial<<<dim3(64, KSPLIT), 256, 0, stream>>>(A, Bp, part);
  k3_reduce<<<4096, 256, 0, stream>>>(part, out);
}